// Round 1
// baseline (756.617 us; speedup 1.0000x reference)
//
#include <hip/hip_runtime.h>
#include <math.h>

#define NN 16384
#define EE 262144

// ---- workspace layout (units of 4-byte elements) ----
#define OFF_CNT     0                      // 2*NN ints
#define OFF_FILL    (2*NN)                 // 2*NN ints
#define OFF_ROWPTR  (4*NN)                 // 2*(NN+1) ints
#define OFF_COLSRC  98816                  // 2*EE ints
#define OFF_H       623104                 // 2*NN*64 floats
#define OFF_HN      (OFF_H  + 2*NN*64)     // 2*NN*64 floats
#define OFF_Q       (OFF_HN + 2*NN*64)     // NN*256 floats
#define OFF_K       (OFF_Q  + NN*256)      // NN*256 floats
#define OFF_V       (OFF_K  + NN*256)      // NN*256 floats
#define OFF_R       (OFF_V  + NN*256)      // NN*64 floats
#define OFF_FF      OFF_Q                  // reuse Q+K region: 2*NN*256 floats

// ======================= CSR build =======================
__global__ void count_kernel(const int* __restrict__ ei, int* __restrict__ cnt) {
  int idx = blockIdx.x * 256 + threadIdx.x;
  if (idx >= 2 * EE) return;
  int et = idx >> 18;            // / EE
  int j  = idx & (EE - 1);
  int dst = ei[et * 2 * EE + EE + j];
  atomicAdd(&cnt[et * NN + dst], 1);
}

__global__ __launch_bounds__(1024) void scan_kernel(const int* __restrict__ cnt,
                                                    int* __restrict__ rowptr,
                                                    int* __restrict__ fill) {
  int et = blockIdx.x;
  const int* c = cnt + et * NN;
  __shared__ int sums[1024];
  int tid = threadIdx.x;
  int base = tid * 16;
  int loc[16];
  int s = 0;
#pragma unroll
  for (int i = 0; i < 16; ++i) { loc[i] = s; s += c[base + i]; }
  sums[tid] = s;
  __syncthreads();
  for (int off = 1; off < 1024; off <<= 1) {
    int v = 0;
    if (tid >= off) v = sums[tid - off];
    __syncthreads();
    if (tid >= off) sums[tid] += v;
    __syncthreads();
  }
  int ebase = (tid == 0) ? 0 : sums[tid - 1];
  int* rp = rowptr + et * (NN + 1);
  int* fl = fill + et * NN;
#pragma unroll
  for (int i = 0; i < 16; ++i) {
    rp[base + i] = ebase + loc[i];
    fl[base + i] = ebase + loc[i];
  }
  if (tid == 1023) rp[NN] = sums[1023];
}

__global__ void scatter_kernel(const int* __restrict__ ei, int* __restrict__ fill,
                               int* __restrict__ colsrc) {
  int idx = blockIdx.x * 256 + threadIdx.x;
  if (idx >= 2 * EE) return;
  int et = idx >> 18;
  int j  = idx & (EE - 1);
  int src = ei[et * 2 * EE + j];
  int dst = ei[et * 2 * EE + EE + j];
  int pos = atomicAdd(&fill[et * NN + dst], 1);
  colsrc[et * EE + pos] = src;
}

// ======================= generic tiled GEMM =======================
// C[M,Nc] = A[M,K] @ B[K,Nc] + bias (+bias2) (+add) (gelu optional)
// tile 128 rows x 64 cols, block 256, microtile 4x8
struct GemmDesc {
  const float *A, *B, *bias, *bias2, *add;
  float* C;
  int K, Ncols, tile0, ntiles, gelu;
};
struct GemmPack { GemmDesc d[8]; int nd; };

__global__ __launch_bounds__(256) void gemm_multi(GemmPack p) {
  int y = blockIdx.y;
  int di = 0;
  for (int i = 0; i < p.nd; ++i)
    if (y >= p.d[i].tile0 && y < p.d[i].tile0 + p.d[i].ntiles) di = i;
  GemmDesc g = p.d[di];
  const int col0 = (y - g.tile0) * 64;
  const int row0 = blockIdx.x * 128;
  const int tid = threadIdx.x;

  __shared__ float As[128 * 65];
  __shared__ float Bs[64 * 64];

  float acc[4][8];
#pragma unroll
  for (int r = 0; r < 4; ++r)
#pragma unroll
    for (int c = 0; c < 8; ++c) acc[r][c] = 0.f;

  const int i4 = (tid >> 3) << 2;   // 0..124 step 4
  const int j8 = (tid & 7) << 3;    // 0..56 step 8

  for (int kt = 0; kt < g.K; kt += 64) {
    // A tile: 128x64 -> LDS row-major, stride 65
#pragma unroll
    for (int it = 0; it < 8; ++it) {
      int fi = it * 256 + tid;          // float4 idx 0..2047
      int grow = fi >> 4;
      int kq = (fi & 15) << 2;
      float4 a = *(const float4*)(g.A + (size_t)(row0 + grow) * g.K + kt + kq);
      float* dp = &As[grow * 65 + kq];
      dp[0] = a.x; dp[1] = a.y; dp[2] = a.z; dp[3] = a.w;
    }
    // B tile: 64x64
#pragma unroll
    for (int it = 0; it < 4; ++it) {
      int fi = it * 256 + tid;          // 0..1023
      int kk = fi >> 4;
      int cq = (fi & 15) << 2;
      *(float4*)&Bs[kk * 64 + cq] =
          *(const float4*)(g.B + (size_t)(kt + kk) * g.Ncols + col0 + cq);
    }
    __syncthreads();
#pragma unroll 8
    for (int k = 0; k < 64; ++k) {
      float4 b0 = *(float4*)&Bs[k * 64 + j8];
      float4 b1 = *(float4*)&Bs[k * 64 + j8 + 4];
#pragma unroll
      for (int r = 0; r < 4; ++r) {
        float a = As[(i4 + r) * 65 + k];
        acc[r][0] += a * b0.x; acc[r][1] += a * b0.y;
        acc[r][2] += a * b0.z; acc[r][3] += a * b0.w;
        acc[r][4] += a * b1.x; acc[r][5] += a * b1.y;
        acc[r][6] += a * b1.z; acc[r][7] += a * b1.w;
      }
    }
    __syncthreads();
  }

  float bv[8];
#pragma unroll
  for (int c = 0; c < 8; ++c) {
    float b = g.bias ? g.bias[col0 + j8 + c] : 0.f;
    if (g.bias2) b += g.bias2[col0 + j8 + c];
    bv[c] = b;
  }
#pragma unroll
  for (int r = 0; r < 4; ++r) {
    size_t row = row0 + i4 + r;
    float v[8];
#pragma unroll
    for (int c = 0; c < 8; ++c) v[c] = acc[r][c] + bv[c];
    if (g.add) {
      const float* ap = g.add + row * g.Ncols + col0 + j8;
#pragma unroll
      for (int c = 0; c < 8; ++c) v[c] += ap[c];
    }
    if (g.gelu) {
#pragma unroll
      for (int c = 0; c < 8; ++c)
        v[c] = 0.5f * v[c] * (1.f + erff(v[c] * 0.70710678118654752f));
    }
    float* cp = g.C + row * g.Ncols + col0 + j8;
    *(float4*)cp = make_float4(v[0], v[1], v[2], v[3]);
    *(float4*)(cp + 4) = make_float4(v[4], v[5], v[6], v[7]);
  }
}

// ======================= edge aggregation (one wave / dst node) =======================
// lane = head*16 + c4 ; each lane owns 4 channels of one head (float4)
struct AggPack {
  const float *Q, *K, *V, *R, *Wb;
  float* out;
  const int *rowptr, *colsrc;
};

__global__ __launch_bounds__(256) void agg_kernel(AggPack p) {
  int wid = threadIdx.x >> 6;
  int lane = threadIdx.x & 63;
  int node = blockIdx.x * 4 + wid;
  int c4 = lane & 15;
  int cb = ((lane >> 4) << 6) + (c4 << 2);   // head*64 + c4*4

  int start = p.rowptr[node], end = p.rowptr[node + 1];
  float4 q = *(const float4*)(p.Q + (size_t)node * 256 + cb);
  float m = -1e30f, dnm = 0.f;
  float ax = 0.f, ay = 0.f, az = 0.f, aw = 0.f;

  for (int j = start; j < end; ++j) {
    int s = p.colsrc[j];
    float4 kv = *(const float4*)(p.K + (size_t)s * 256 + cb);
    float pd = q.x * kv.x + q.y * kv.y + q.z * kv.z + q.w * kv.w;
    pd += __shfl_xor(pd, 1);
    pd += __shfl_xor(pd, 2);
    pd += __shfl_xor(pd, 4);
    pd += __shfl_xor(pd, 8);
    float logit = pd * 0.125f;
    float nm = fmaxf(m, logit);
    float sc = __expf(m - nm);
    float w = __expf(logit - nm);
    m = nm;
    float4 vv = *(const float4*)(p.V + (size_t)s * 256 + cb);
    dnm = dnm * sc + w;
    ax = ax * sc + w * vv.x;
    ay = ay * sc + w * vv.y;
    az = az * sc + w * vv.z;
    aw = aw * sc + w * vv.w;
  }
  float inv = (end > start) ? (0.25f / dnm) : 0.f;
  float ox = ax * inv, oy = ay * inv, oz = az * inv, ow = aw * inv;
  // sum over heads (quarters)
  ox += __shfl_xor(ox, 16); ox += __shfl_xor(ox, 32);
  oy += __shfl_xor(oy, 16); oy += __shfl_xor(oy, 32);
  oz += __shfl_xor(oz, 16); oz += __shfl_xor(oz, 32);
  ow += __shfl_xor(ow, 16); ow += __shfl_xor(ow, 32);

  int cc = c4 << 2;
  float4 r = *(const float4*)(p.R + (size_t)node * 64 + cc);
  const float* wb = p.Wb;
  float part = ox * wb[cc] + oy * wb[cc + 1] + oz * wb[cc + 2] + ow * wb[cc + 3]
             + r.x * wb[64 + cc] + r.y * wb[64 + cc + 1]
             + r.z * wb[64 + cc + 2] + r.w * wb[64 + cc + 3]
             + (ox - r.x) * wb[128 + cc] + (oy - r.y) * wb[128 + cc + 1]
             + (oz - r.z) * wb[128 + cc + 2] + (ow - r.w) * wb[128 + cc + 3];
  part += __shfl_xor(part, 1);
  part += __shfl_xor(part, 2);
  part += __shfl_xor(part, 4);
  part += __shfl_xor(part, 8);
  float beta = 1.f / (1.f + __expf(-part));
  if (lane < 16) {
    float4 res;
    res.x = beta * r.x + (1.f - beta) * ox;
    res.y = beta * r.y + (1.f - beta) * oy;
    res.z = beta * r.z + (1.f - beta) * oz;
    res.w = beta * r.w + (1.f - beta) * ow;
    *(float4*)(p.out + (size_t)node * 64 + cc) = res;
  }
}

// ======================= LayerNorm (one wave / row) =======================
__global__ __launch_bounds__(256) void ln_kernel(const float* __restrict__ h,
                                                 float* __restrict__ hn,
                                                 const float* __restrict__ g,
                                                 const float* __restrict__ b) {
  int wid = threadIdx.x >> 6;
  int lane = threadIdx.x & 63;
  size_t row = (size_t)blockIdx.x * 4 + wid;
  int t = row >= NN;
  float v = h[row * 64 + lane] + hn[row * 64 + lane];
  float s = v;
  s += __shfl_xor(s, 1);  s += __shfl_xor(s, 2);  s += __shfl_xor(s, 4);
  s += __shfl_xor(s, 8);  s += __shfl_xor(s, 16); s += __shfl_xor(s, 32);
  float mu = s * (1.f / 64.f);
  float dv = v - mu;
  float s2 = dv * dv;
  s2 += __shfl_xor(s2, 1);  s2 += __shfl_xor(s2, 2);  s2 += __shfl_xor(s2, 4);
  s2 += __shfl_xor(s2, 8);  s2 += __shfl_xor(s2, 16); s2 += __shfl_xor(s2, 32);
  float var = s2 * (1.f / 64.f);
  float y = dv * rsqrtf(var + 1e-5f) * g[t * 64 + lane] + b[t * 64 + lane];
  hn[row * 64 + lane] = y;
}

// ======================= host =======================
static void add_desc(GemmPack& p, int& tiles, const float* A, const float* B,
                     const float* bias, const float* bias2, const float* add,
                     float* C, int K, int Nc, int gelu) {
  GemmDesc& g = p.d[p.nd++];
  g.A = A; g.B = B; g.bias = bias; g.bias2 = bias2; g.add = add; g.C = C;
  g.K = K; g.Ncols = Nc; g.tile0 = tiles; g.ntiles = Nc / 64; g.gelu = gelu;
  tiles += g.ntiles;
}

extern "C" void kernel_launch(void* const* d_in, const int* in_sizes, int n_in,
                              void* d_out, int out_size, void* d_ws, size_t ws_size,
                              hipStream_t stream) {
  const float* x        = (const float*)d_in[0];
  const int*   ei       = (const int*)d_in[1];
  const float* W_in     = (const float*)d_in[2];
  const float* b_in     = (const float*)d_in[3];
  const float* type_emb = (const float*)d_in[4];
  const float* pos      = (const float*)d_in[5];
  const float* Wq       = (const float*)d_in[6];
  const float* bq       = (const float*)d_in[7];
  const float* Wk       = (const float*)d_in[8];
  const float* bk       = (const float*)d_in[9];
  const float* Wv       = (const float*)d_in[10];
  const float* bv       = (const float*)d_in[11];
  const float* Wskip    = (const float*)d_in[12];
  const float* bskip    = (const float*)d_in[13];
  const float* Wbeta    = (const float*)d_in[14];
  const float* ln_g     = (const float*)d_in[15];
  const float* ln_b     = (const float*)d_in[16];
  const float* ff_W1    = (const float*)d_in[17];
  const float* ff_b1    = (const float*)d_in[18];
  const float* ff_W2    = (const float*)d_in[19];
  const float* ff_b2    = (const float*)d_in[20];
  const float* W_out    = (const float*)d_in[21];
  const float* b_out    = (const float*)d_in[22];
  float* out = (float*)d_out;

  int*   wsi = (int*)d_ws;
  float* wsf = (float*)d_ws;
  int* cnt    = wsi + OFF_CNT;
  int* fill   = wsi + OFF_FILL;
  int* rowptr = wsi + OFF_ROWPTR;
  int* colsrc = wsi + OFF_COLSRC;
  float* H  = wsf + OFF_H;
  float* HN = wsf + OFF_HN;
  float* Qb = wsf + OFF_Q;
  float* Kb = wsf + OFF_K;
  float* Vb = wsf + OFF_V;
  float* Rb = wsf + OFF_R;
  float* FFb = wsf + OFF_FF;

  // ---- CSR build (edge_index is constant across layers) ----
  hipMemsetAsync(cnt, 0, 2 * NN * sizeof(int), stream);
  count_kernel<<<dim3(2 * EE / 256), dim3(256), 0, stream>>>(ei, cnt);
  scan_kernel<<<dim3(2), dim3(1024), 0, stream>>>(cnt, rowptr, fill);
  scatter_kernel<<<dim3(2 * EE / 256), dim3(256), 0, stream>>>(ei, fill, colsrc);

  // ---- input projection: h[t] = x[t]@W_in[t] + b_in + type_emb + pos ----
  {
    GemmPack p{}; int tiles = 0;
    for (int t = 0; t < 2; ++t)
      add_desc(p, tiles, x + (size_t)t * NN * 64, W_in + t * 64 * 64,
               b_in + t * 64, type_emb + t * 64, pos + (size_t)t * NN * 64,
               H + (size_t)t * NN * 64, 64, 64, 0);
    gemm_multi<<<dim3(128, tiles), dim3(256), 0, stream>>>(p);
  }

  for (int l = 0; l < 2; ++l) {
    for (int et = 0; et < 2; ++et) {
      int s = et, d = 1 - et;
      int we = l * 2 + et;
      const float* hs = H + (size_t)s * NN * 64;
      const float* hd = H + (size_t)d * NN * 64;
      GemmPack p{}; int tiles = 0;
      add_desc(p, tiles, hd, Wq + (size_t)we * 64 * 256, bq + we * 256,
               nullptr, nullptr, Qb, 64, 256, 0);
      add_desc(p, tiles, hs, Wk + (size_t)we * 64 * 256, bk + we * 256,
               nullptr, nullptr, Kb, 64, 256, 0);
      add_desc(p, tiles, hs, Wv + (size_t)we * 64 * 256, bv + we * 256,
               nullptr, nullptr, Vb, 64, 256, 0);
      add_desc(p, tiles, hd, Wskip + (size_t)we * 64 * 64, bskip + we * 64,
               nullptr, nullptr, Rb, 64, 64, 0);
      gemm_multi<<<dim3(128, tiles), dim3(256), 0, stream>>>(p);

      AggPack ap;
      ap.Q = Qb; ap.K = Kb; ap.V = Vb; ap.R = Rb;
      ap.Wb = Wbeta + we * 192;
      ap.out = HN + (size_t)d * NN * 64;
      ap.rowptr = rowptr + et * (NN + 1);
      ap.colsrc = colsrc + et * EE;
      agg_kernel<<<dim3(NN / 4), dim3(256), 0, stream>>>(ap);
    }

    ln_kernel<<<dim3(2 * NN / 4), dim3(256), 0, stream>>>(H, HN,
                                                          ln_g + l * 128,
                                                          ln_b + l * 128);
    {
      GemmPack p{}; int tiles = 0;
      for (int t = 0; t < 2; ++t)
        add_desc(p, tiles, HN + (size_t)t * NN * 64,
                 ff_W1 + (size_t)(l * 2 + t) * 64 * 256,
                 ff_b1 + (l * 2 + t) * 256, nullptr, nullptr,
                 FFb + (size_t)t * NN * 256, 64, 256, 1);
      gemm_multi<<<dim3(128, tiles), dim3(256), 0, stream>>>(p);
    }
    {
      GemmPack p{}; int tiles = 0;
      for (int t = 0; t < 2; ++t)
        add_desc(p, tiles, FFb + (size_t)t * NN * 256,
                 ff_W2 + (size_t)(l * 2 + t) * 256 * 64,
                 ff_b2 + (l * 2 + t) * 64, nullptr,
                 HN + (size_t)t * NN * 64,          // residual hr
                 H + (size_t)t * NN * 64, 256, 64, 0);
      gemm_multi<<<dim3(128, tiles), dim3(256), 0, stream>>>(p);
    }
  }

  // ---- output projection ----
  {
    GemmPack p{}; int tiles = 0;
    for (int t = 0; t < 2; ++t)
      add_desc(p, tiles, H + (size_t)t * NN * 64, W_out + t * 64 * 64,
               b_out + t * 64, nullptr, nullptr,
               out + (size_t)t * NN * 64, 64, 64, 0);
    gemm_multi<<<dim3(128, tiles), dim3(256), 0, stream>>>(p);
  }
}

// Round 2
// 539.864 us; speedup vs baseline: 1.4015x; 1.4015x over previous
//
#include <hip/hip_runtime.h>
#include <math.h>

#define NN 16384
#define EE 262144

typedef __bf16 v8bf __attribute__((ext_vector_type(8)));
typedef __bf16 v4bf __attribute__((ext_vector_type(4)));
typedef float  v4f  __attribute__((ext_vector_type(4)));

// ---- workspace layout (units of 4-byte elements) ----
#define OFF_CNT     0                      // 2*NN ints
#define OFF_FILL    (2*NN)                 // 2*NN ints
#define OFF_ROWPTR  (4*NN)                 // 2*(NN+1) ints
#define OFF_COLSRC  98816                  // 2*EE ints
#define OFF_H       623104                 // 2*NN*64 floats
#define OFF_HN      (OFF_H  + 2*NN*64)     // 2*NN*64 floats
#define OFF_Q       (OFF_HN + 2*NN*64)     // NN*256 floats
#define OFF_K       (OFF_Q  + NN*256)      // NN*256 ushorts (bf16) in float-sized slot
#define OFF_V       (OFF_K  + NN*256)      // NN*256 ushorts (bf16)
#define OFF_R       (OFF_V  + NN*256)      // NN*64 floats
#define OFF_FF      OFF_Q                  // reuse Q+K region: 2*NN*256 floats

__device__ __forceinline__ float b2f(unsigned short u) {
  return __uint_as_float(((unsigned)u) << 16);
}
__device__ __forceinline__ unsigned short f2b(float f) {
  __bf16 h = (__bf16)f;
  return *(unsigned short*)&h;
}

// ======================= CSR build =======================
__global__ void count_kernel(const int* __restrict__ ei, int* __restrict__ cnt) {
  int idx = blockIdx.x * 256 + threadIdx.x;
  if (idx >= 2 * EE) return;
  int et = idx >> 18;
  int j  = idx & (EE - 1);
  int dst = ei[et * 2 * EE + EE + j];
  atomicAdd(&cnt[et * NN + dst], 1);
}

__global__ __launch_bounds__(1024) void scan_kernel(const int* __restrict__ cnt,
                                                    int* __restrict__ rowptr,
                                                    int* __restrict__ fill) {
  int et = blockIdx.x;
  const int* c = cnt + et * NN;
  __shared__ int sums[1024];
  int tid = threadIdx.x;
  int base = tid * 16;
  int loc[16];
  int s = 0;
#pragma unroll
  for (int i = 0; i < 16; ++i) { loc[i] = s; s += c[base + i]; }
  sums[tid] = s;
  __syncthreads();
  for (int off = 1; off < 1024; off <<= 1) {
    int v = 0;
    if (tid >= off) v = sums[tid - off];
    __syncthreads();
    if (tid >= off) sums[tid] += v;
    __syncthreads();
  }
  int ebase = (tid == 0) ? 0 : sums[tid - 1];
  int* rp = rowptr + et * (NN + 1);
  int* fl = fill + et * NN;
#pragma unroll
  for (int i = 0; i < 16; ++i) {
    rp[base + i] = ebase + loc[i];
    fl[base + i] = ebase + loc[i];
  }
  if (tid == 1023) rp[NN] = sums[1023];
}

__global__ void scatter_kernel(const int* __restrict__ ei, int* __restrict__ fill,
                               int* __restrict__ colsrc) {
  int idx = blockIdx.x * 256 + threadIdx.x;
  if (idx >= 2 * EE) return;
  int et = idx >> 18;
  int j  = idx & (EE - 1);
  int src = ei[et * 2 * EE + j];
  int dst = ei[et * 2 * EE + EE + j];
  int pos = atomicAdd(&fill[et * NN + dst], 1);
  colsrc[et * EE + pos] = src;
}

// ======================= bf16 MFMA tiled GEMM =======================
// C[M,Nc] = A[M,K] @ B[K,Nc] + bias (+bias2) (+add) (gelu) ; A,B fp32 in
// global, converted to bf16 in LDS; accumulate fp32 via mfma 16x16x32.
// block 256 = 4 waves; tile 128 rows x 64 cols; wave: 32 rows x 64 cols.
struct GemmDesc {
  const float *A, *B, *bias, *bias2, *add;
  void* C;
  int K, Ncols, tile0, ntiles, gelu, obf;
};
struct GemmPack { GemmDesc d[8]; int nd; };

#define LDA 72   // padded bf16 row stride (2-way bank alias only)

__global__ __launch_bounds__(256) void gemm_mfma(GemmPack p) {
  int y = blockIdx.y;
  int di = 0;
  for (int i = 0; i < p.nd; ++i)
    if (y >= p.d[i].tile0 && y < p.d[i].tile0 + p.d[i].ntiles) di = i;
  GemmDesc g = p.d[di];
  const int col0 = (y - g.tile0) * 64;
  const int row0 = blockIdx.x * 128;
  const int tid = threadIdx.x;
  const int w = tid >> 6, lane = tid & 63;
  const int l16 = lane & 15, quad = lane >> 4;

  __shared__ __bf16 As[128 * LDA];
  __shared__ __bf16 Bs[64 * LDA];

  v4f acc[2][4];
#pragma unroll
  for (int rt = 0; rt < 2; ++rt)
#pragma unroll
    for (int ct = 0; ct < 4; ++ct)
#pragma unroll
      for (int r = 0; r < 4; ++r) acc[rt][ct][r] = 0.f;

  for (int kt = 0; kt < g.K; kt += 64) {
    // A tile: 128x64 fp32 -> bf16 LDS row-major stride LDA
#pragma unroll
    for (int it = 0; it < 8; ++it) {
      int fi = it * 256 + tid;          // float4 idx 0..2047
      int grow = fi >> 4;
      int kq = (fi & 15) << 2;
      float4 a = *(const float4*)(g.A + (size_t)(row0 + grow) * g.K + kt + kq);
      v4bf c = { (__bf16)a.x, (__bf16)a.y, (__bf16)a.z, (__bf16)a.w };
      *(v4bf*)&As[grow * LDA + kq] = c;
    }
    // B tile: 64x64 fp32 -> bf16 LDS TRANSPOSED (Bs[n][k])
#pragma unroll
    for (int it = 0; it < 4; ++it) {
      int fi = it * 256 + tid;          // 0..1023
      int kk = fi >> 4;
      int nq = (fi & 15) << 2;
      float4 b = *(const float4*)(g.B + (size_t)(kt + kk) * g.Ncols + col0 + nq);
      Bs[(nq + 0) * LDA + kk] = (__bf16)b.x;
      Bs[(nq + 1) * LDA + kk] = (__bf16)b.y;
      Bs[(nq + 2) * LDA + kk] = (__bf16)b.z;
      Bs[(nq + 3) * LDA + kk] = (__bf16)b.w;
    }
    __syncthreads();
#pragma unroll
    for (int ks = 0; ks < 2; ++ks) {
      v8bf a0 = *(v8bf*)&As[(w * 32 + l16) * LDA + ks * 32 + quad * 8];
      v8bf a1 = *(v8bf*)&As[(w * 32 + 16 + l16) * LDA + ks * 32 + quad * 8];
#pragma unroll
      for (int ct = 0; ct < 4; ++ct) {
        v8bf bb = *(v8bf*)&Bs[(ct * 16 + l16) * LDA + ks * 32 + quad * 8];
        acc[0][ct] = __builtin_amdgcn_mfma_f32_16x16x32_bf16(a0, bb, acc[0][ct], 0, 0, 0);
        acc[1][ct] = __builtin_amdgcn_mfma_f32_16x16x32_bf16(a1, bb, acc[1][ct], 0, 0, 0);
      }
    }
    __syncthreads();
  }

  // epilogue: C/D layout col=lane&15, row=quad*4+reg
  float bias_c[4];
#pragma unroll
  for (int ct = 0; ct < 4; ++ct) {
    int col = col0 + ct * 16 + l16;
    float b = g.bias ? g.bias[col] : 0.f;
    if (g.bias2) b += g.bias2[col];
    bias_c[ct] = b;
  }
#pragma unroll
  for (int rt = 0; rt < 2; ++rt)
#pragma unroll
    for (int r = 0; r < 4; ++r) {
      size_t row = row0 + w * 32 + rt * 16 + quad * 4 + r;
#pragma unroll
      for (int ct = 0; ct < 4; ++ct) {
        int col = col0 + ct * 16 + l16;
        float v = acc[rt][ct][r] + bias_c[ct];
        if (g.add) v += g.add[row * g.Ncols + col];
        if (g.gelu) v = 0.5f * v * (1.f + erff(v * 0.70710678118654752f));
        if (g.obf) ((unsigned short*)g.C)[row * g.Ncols + col] = f2b(v);
        else       ((float*)g.C)[row * g.Ncols + col] = v;
      }
    }
}

// ======================= edge aggregation (one wave / dst node) =======================
// lane = head*16 + c4 ; each lane owns 4 channels of one head. K/V are bf16.
struct AggPack {
  const float* Q;
  const unsigned short *K, *V;
  const float *R, *Wb;
  float* out;
  const int *rowptr, *colsrc;
};

__global__ __launch_bounds__(256) void agg_kernel(AggPack p) {
  int wid = threadIdx.x >> 6;
  int lane = threadIdx.x & 63;
  int node = blockIdx.x * 4 + wid;
  int c4 = lane & 15;
  int cb = ((lane >> 4) << 6) + (c4 << 2);   // head*64 + c4*4

  int start = p.rowptr[node], end = p.rowptr[node + 1];
  float4 q = *(const float4*)(p.Q + (size_t)node * 256 + cb);
  float m = -1e30f, dnm = 0.f;
  float ax = 0.f, ay = 0.f, az = 0.f, aw = 0.f;

  // 1-deep software pipeline over the gather loop
  ushort4 kA, vA;
  if (start < end) {
    int s0 = p.colsrc[start];
    kA = *(const ushort4*)(p.K + ((size_t)s0 << 8) + cb);
    vA = *(const ushort4*)(p.V + ((size_t)s0 << 8) + cb);
  }
  for (int j = start; j < end; ++j) {
    ushort4 k0 = kA, v0 = vA;
    int jn = j + 1;
    if (jn < end) {
      int sn = p.colsrc[jn];
      kA = *(const ushort4*)(p.K + ((size_t)sn << 8) + cb);
      vA = *(const ushort4*)(p.V + ((size_t)sn << 8) + cb);
    }
    float pd = q.x * b2f(k0.x) + q.y * b2f(k0.y) + q.z * b2f(k0.z) + q.w * b2f(k0.w);
    pd += __shfl_xor(pd, 1);
    pd += __shfl_xor(pd, 2);
    pd += __shfl_xor(pd, 4);
    pd += __shfl_xor(pd, 8);
    float logit = pd * 0.125f;
    float nm = fmaxf(m, logit);
    float sc = __expf(m - nm);
    float wgt = __expf(logit - nm);
    m = nm;
    dnm = dnm * sc + wgt;
    ax = ax * sc + wgt * b2f(v0.x);
    ay = ay * sc + wgt * b2f(v0.y);
    az = az * sc + wgt * b2f(v0.z);
    aw = aw * sc + wgt * b2f(v0.w);
  }
  float inv = (end > start) ? (0.25f / dnm) : 0.f;
  float ox = ax * inv, oy = ay * inv, oz = az * inv, ow = aw * inv;
  // sum over heads (lane quarters)
  ox += __shfl_xor(ox, 16); ox += __shfl_xor(ox, 32);
  oy += __shfl_xor(oy, 16); oy += __shfl_xor(oy, 32);
  oz += __shfl_xor(oz, 16); oz += __shfl_xor(oz, 32);
  ow += __shfl_xor(ow, 16); ow += __shfl_xor(ow, 32);

  int cc = c4 << 2;
  float4 r = *(const float4*)(p.R + (size_t)node * 64 + cc);
  const float* wb = p.Wb;
  float part = ox * wb[cc] + oy * wb[cc + 1] + oz * wb[cc + 2] + ow * wb[cc + 3]
             + r.x * wb[64 + cc] + r.y * wb[64 + cc + 1]
             + r.z * wb[64 + cc + 2] + r.w * wb[64 + cc + 3]
             + (ox - r.x) * wb[128 + cc] + (oy - r.y) * wb[128 + cc + 1]
             + (oz - r.z) * wb[128 + cc + 2] + (ow - r.w) * wb[128 + cc + 3];
  part += __shfl_xor(part, 1);
  part += __shfl_xor(part, 2);
  part += __shfl_xor(part, 4);
  part += __shfl_xor(part, 8);
  float beta = 1.f / (1.f + __expf(-part));
  if (lane < 16) {
    float4 res;
    res.x = beta * r.x + (1.f - beta) * ox;
    res.y = beta * r.y + (1.f - beta) * oy;
    res.z = beta * r.z + (1.f - beta) * oz;
    res.w = beta * r.w + (1.f - beta) * ow;
    *(float4*)(p.out + (size_t)node * 64 + cc) = res;
  }
}

// ======================= LayerNorm (one wave / row) =======================
__global__ __launch_bounds__(256) void ln_kernel(const float* __restrict__ h,
                                                 float* __restrict__ hn,
                                                 const float* __restrict__ g,
                                                 const float* __restrict__ b) {
  int wid = threadIdx.x >> 6;
  int lane = threadIdx.x & 63;
  size_t row = (size_t)blockIdx.x * 4 + wid;
  int t = row >= NN;
  float v = h[row * 64 + lane] + hn[row * 64 + lane];
  float s = v;
  s += __shfl_xor(s, 1);  s += __shfl_xor(s, 2);  s += __shfl_xor(s, 4);
  s += __shfl_xor(s, 8);  s += __shfl_xor(s, 16); s += __shfl_xor(s, 32);
  float mu = s * (1.f / 64.f);
  float dv = v - mu;
  float s2 = dv * dv;
  s2 += __shfl_xor(s2, 1);  s2 += __shfl_xor(s2, 2);  s2 += __shfl_xor(s2, 4);
  s2 += __shfl_xor(s2, 8);  s2 += __shfl_xor(s2, 16); s2 += __shfl_xor(s2, 32);
  float var = s2 * (1.f / 64.f);
  float y = dv * rsqrtf(var + 1e-5f) * g[t * 64 + lane] + b[t * 64 + lane];
  hn[row * 64 + lane] = y;
}

// ======================= host =======================
static void add_desc(GemmPack& p, int& tiles, const float* A, const float* B,
                     const float* bias, const float* bias2, const float* add,
                     void* C, int K, int Nc, int gelu, int obf) {
  GemmDesc& g = p.d[p.nd++];
  g.A = A; g.B = B; g.bias = bias; g.bias2 = bias2; g.add = add; g.C = C;
  g.K = K; g.Ncols = Nc; g.tile0 = tiles; g.ntiles = Nc / 64; g.gelu = gelu;
  g.obf = obf;
  tiles += g.ntiles;
}

extern "C" void kernel_launch(void* const* d_in, const int* in_sizes, int n_in,
                              void* d_out, int out_size, void* d_ws, size_t ws_size,
                              hipStream_t stream) {
  const float* x        = (const float*)d_in[0];
  const int*   ei       = (const int*)d_in[1];
  const float* W_in     = (const float*)d_in[2];
  const float* b_in     = (const float*)d_in[3];
  const float* type_emb = (const float*)d_in[4];
  const float* pos      = (const float*)d_in[5];
  const float* Wq       = (const float*)d_in[6];
  const float* bq       = (const float*)d_in[7];
  const float* Wk       = (const float*)d_in[8];
  const float* bk       = (const float*)d_in[9];
  const float* Wv       = (const float*)d_in[10];
  const float* bv       = (const float*)d_in[11];
  const float* Wskip    = (const float*)d_in[12];
  const float* bskip    = (const float*)d_in[13];
  const float* Wbeta    = (const float*)d_in[14];
  const float* ln_g     = (const float*)d_in[15];
  const float* ln_b     = (const float*)d_in[16];
  const float* ff_W1    = (const float*)d_in[17];
  const float* ff_b1    = (const float*)d_in[18];
  const float* ff_W2    = (const float*)d_in[19];
  const float* ff_b2    = (const float*)d_in[20];
  const float* W_out    = (const float*)d_in[21];
  const float* b_out    = (const float*)d_in[22];
  float* out = (float*)d_out;

  int*   wsi = (int*)d_ws;
  float* wsf = (float*)d_ws;
  int* cnt    = wsi + OFF_CNT;
  int* fill   = wsi + OFF_FILL;
  int* rowptr = wsi + OFF_ROWPTR;
  int* colsrc = wsi + OFF_COLSRC;
  float* H  = wsf + OFF_H;
  float* HN = wsf + OFF_HN;
  float* Qb = wsf + OFF_Q;
  unsigned short* Kb = (unsigned short*)(wsf + OFF_K);
  unsigned short* Vb = (unsigned short*)(wsf + OFF_V);
  float* Rb = wsf + OFF_R;
  float* FFb = wsf + OFF_FF;

  // ---- CSR build ----
  hipMemsetAsync(cnt, 0, 2 * NN * sizeof(int), stream);
  count_kernel<<<dim3(2 * EE / 256), dim3(256), 0, stream>>>(ei, cnt);
  scan_kernel<<<dim3(2), dim3(1024), 0, stream>>>(cnt, rowptr, fill);
  scatter_kernel<<<dim3(2 * EE / 256), dim3(256), 0, stream>>>(ei, fill, colsrc);

  // ---- input projection: h[t] = x[t]@W_in[t] + b_in + type_emb + pos ----
  {
    GemmPack p{}; int tiles = 0;
    for (int t = 0; t < 2; ++t)
      add_desc(p, tiles, x + (size_t)t * NN * 64, W_in + t * 64 * 64,
               b_in + t * 64, type_emb + t * 64, pos + (size_t)t * NN * 64,
               H + (size_t)t * NN * 64, 64, 64, 0, 0);
    gemm_mfma<<<dim3(128, tiles), dim3(256), 0, stream>>>(p);
  }

  for (int l = 0; l < 2; ++l) {
    for (int et = 0; et < 2; ++et) {
      int s = et, d = 1 - et;
      int we = l * 2 + et;
      const float* hs = H + (size_t)s * NN * 64;
      const float* hd = H + (size_t)d * NN * 64;
      GemmPack p{}; int tiles = 0;
      add_desc(p, tiles, hd, Wq + (size_t)we * 64 * 256, bq + we * 256,
               nullptr, nullptr, Qb, 64, 256, 0, 0);
      add_desc(p, tiles, hs, Wk + (size_t)we * 64 * 256, bk + we * 256,
               nullptr, nullptr, Kb, 64, 256, 0, 1);
      add_desc(p, tiles, hs, Wv + (size_t)we * 64 * 256, bv + we * 256,
               nullptr, nullptr, Vb, 64, 256, 0, 1);
      add_desc(p, tiles, hd, Wskip + (size_t)we * 64 * 64, bskip + we * 64,
               nullptr, nullptr, Rb, 64, 64, 0, 0);
      gemm_mfma<<<dim3(128, tiles), dim3(256), 0, stream>>>(p);

      AggPack ap;
      ap.Q = Qb; ap.K = Kb; ap.V = Vb; ap.R = Rb;
      ap.Wb = Wbeta + we * 192;
      ap.out = HN + (size_t)d * NN * 64;
      ap.rowptr = rowptr + et * (NN + 1);
      ap.colsrc = colsrc + et * EE;
      agg_kernel<<<dim3(NN / 4), dim3(256), 0, stream>>>(ap);
    }

    ln_kernel<<<dim3(2 * NN / 4), dim3(256), 0, stream>>>(H, HN,
                                                          ln_g + l * 128,
                                                          ln_b + l * 128);
    {
      GemmPack p{}; int tiles = 0;
      for (int t = 0; t < 2; ++t)
        add_desc(p, tiles, HN + (size_t)t * NN * 64,
                 ff_W1 + (size_t)(l * 2 + t) * 64 * 256,
                 ff_b1 + (l * 2 + t) * 256, nullptr, nullptr,
                 FFb + (size_t)t * NN * 256, 64, 256, 1, 0);
      gemm_mfma<<<dim3(128, tiles), dim3(256), 0, stream>>>(p);
    }
    {
      GemmPack p{}; int tiles = 0;
      for (int t = 0; t < 2; ++t)
        add_desc(p, tiles, FFb + (size_t)t * NN * 256,
                 ff_W2 + (size_t)(l * 2 + t) * 256 * 64,
                 ff_b2 + (l * 2 + t) * 64, nullptr,
                 HN + (size_t)t * NN * 64,          // residual hr
                 H + (size_t)t * NN * 64, 256, 64, 0, 0);
      gemm_mfma<<<dim3(128, tiles), dim3(256), 0, stream>>>(p);
    }
  }

  // ---- output projection ----
  {
    GemmPack p{}; int tiles = 0;
    for (int t = 0; t < 2; ++t)
      add_desc(p, tiles, H + (size_t)t * NN * 64, W_out + t * 64 * 64,
               b_out + t * 64, nullptr, nullptr,
               out + (size_t)t * NN * 64, 64, 64, 0, 0);
    gemm_mfma<<<dim3(128, tiles), dim3(256), 0, stream>>>(p);
  }
}

// Round 3
// 473.972 us; speedup vs baseline: 1.5963x; 1.1390x over previous
//
#include <hip/hip_runtime.h>
#include <math.h>

#define NN 16384
#define EE 262144

typedef __bf16 v8bf __attribute__((ext_vector_type(8)));
typedef __bf16 v4bf __attribute__((ext_vector_type(4)));
typedef float  v4f  __attribute__((ext_vector_type(4)));

// ---- workspace layout (units of 4-byte elements) ----
#define OFF_CNT     0                      // 2*NN ints
#define OFF_FILL    (2*NN)                 // 2*NN ints
#define OFF_ROWPTR  (4*NN)                 // 2*(NN+1) ints
#define OFF_COLSRC  98816                  // 2*EE ints
#define OFF_H       623104                 // 2*NN*64 floats
#define OFF_HN      (OFF_H  + 2*NN*64)     // 2*NN*64 floats
#define OFF_Q       (OFF_HN + 2*NN*64)     // NN*256 bf16
#define OFF_K       (OFF_Q  + NN*256)      // NN*256 bf16 (slot sized in floats, half used)
#define OFF_V       (OFF_K  + NN*256)      // NN*256 bf16
#define OFF_R       (OFF_V  + NN*256)      // NN*64 floats

__device__ __forceinline__ float b2f(unsigned short u) {
  return __uint_as_float(((unsigned)u) << 16);
}
__device__ __forceinline__ unsigned short f2b(float f) {
  __bf16 h = (__bf16)f;
  return *(unsigned short*)&h;
}

// ======================= CSR build =======================
__global__ void count_kernel(const int* __restrict__ ei, int* __restrict__ cnt) {
  int idx = blockIdx.x * 256 + threadIdx.x;
  if (idx >= 2 * EE) return;
  int et = idx >> 18;
  int j  = idx & (EE - 1);
  int dst = ei[et * 2 * EE + EE + j];
  atomicAdd(&cnt[et * NN + dst], 1);
}

__global__ __launch_bounds__(1024) void scan_kernel(const int* __restrict__ cnt,
                                                    int* __restrict__ rowptr,
                                                    int* __restrict__ fill) {
  int et = blockIdx.x;
  const int* c = cnt + et * NN;
  __shared__ int sums[1024];
  int tid = threadIdx.x;
  int base = tid * 16;
  int loc[16];
  int s = 0;
#pragma unroll
  for (int i = 0; i < 16; ++i) { loc[i] = s; s += c[base + i]; }
  sums[tid] = s;
  __syncthreads();
  for (int off = 1; off < 1024; off <<= 1) {
    int v = 0;
    if (tid >= off) v = sums[tid - off];
    __syncthreads();
    if (tid >= off) sums[tid] += v;
    __syncthreads();
  }
  int ebase = (tid == 0) ? 0 : sums[tid - 1];
  int* rp = rowptr + et * (NN + 1);
  int* fl = fill + et * NN;
#pragma unroll
  for (int i = 0; i < 16; ++i) {
    rp[base + i] = ebase + loc[i];
    fl[base + i] = ebase + loc[i];
  }
  if (tid == 1023) rp[NN] = sums[1023];
}

__global__ void scatter_kernel(const int* __restrict__ ei, int* __restrict__ fill,
                               int* __restrict__ colsrc) {
  int idx = blockIdx.x * 256 + threadIdx.x;
  if (idx >= 2 * EE) return;
  int et = idx >> 18;
  int j  = idx & (EE - 1);
  int src = ei[et * 2 * EE + j];
  int dst = ei[et * 2 * EE + EE + j];
  int pos = atomicAdd(&fill[et * NN + dst], 1);
  colsrc[et * EE + pos] = src;
}

// ======================= bf16 MFMA tiled GEMM =======================
struct GemmDesc {
  const float *A, *B, *bias, *bias2, *add;
  void* C;
  int K, Ncols, tile0, ntiles, gelu, obf;
};
struct GemmPack { GemmDesc d[8]; int nd; };

#define LDA 72   // padded bf16 row stride

__global__ __launch_bounds__(256) void gemm_mfma(GemmPack p) {
  int y = blockIdx.y;
  int di = 0;
  for (int i = 0; i < p.nd; ++i)
    if (y >= p.d[i].tile0 && y < p.d[i].tile0 + p.d[i].ntiles) di = i;
  GemmDesc g = p.d[di];
  const int col0 = (y - g.tile0) * 64;
  const int row0 = blockIdx.x * 128;
  const int tid = threadIdx.x;
  const int w = tid >> 6, lane = tid & 63;
  const int l16 = lane & 15, quad = lane >> 4;

  __shared__ __bf16 As[128 * LDA];
  __shared__ __bf16 Bs[64 * LDA];

  v4f acc[2][4];
#pragma unroll
  for (int rt = 0; rt < 2; ++rt)
#pragma unroll
    for (int ct = 0; ct < 4; ++ct)
#pragma unroll
      for (int r = 0; r < 4; ++r) acc[rt][ct][r] = 0.f;

  for (int kt = 0; kt < g.K; kt += 64) {
#pragma unroll
    for (int it = 0; it < 8; ++it) {
      int fi = it * 256 + tid;
      int grow = fi >> 4;
      int kq = (fi & 15) << 2;
      float4 a = *(const float4*)(g.A + (size_t)(row0 + grow) * g.K + kt + kq);
      v4bf c = { (__bf16)a.x, (__bf16)a.y, (__bf16)a.z, (__bf16)a.w };
      *(v4bf*)&As[grow * LDA + kq] = c;
    }
#pragma unroll
    for (int it = 0; it < 4; ++it) {
      int fi = it * 256 + tid;
      int kk = fi >> 4;
      int nq = (fi & 15) << 2;
      float4 b = *(const float4*)(g.B + (size_t)(kt + kk) * g.Ncols + col0 + nq);
      Bs[(nq + 0) * LDA + kk] = (__bf16)b.x;
      Bs[(nq + 1) * LDA + kk] = (__bf16)b.y;
      Bs[(nq + 2) * LDA + kk] = (__bf16)b.z;
      Bs[(nq + 3) * LDA + kk] = (__bf16)b.w;
    }
    __syncthreads();
#pragma unroll
    for (int ks = 0; ks < 2; ++ks) {
      v8bf a0 = *(v8bf*)&As[(w * 32 + l16) * LDA + ks * 32 + quad * 8];
      v8bf a1 = *(v8bf*)&As[(w * 32 + 16 + l16) * LDA + ks * 32 + quad * 8];
#pragma unroll
      for (int ct = 0; ct < 4; ++ct) {
        v8bf bb = *(v8bf*)&Bs[(ct * 16 + l16) * LDA + ks * 32 + quad * 8];
        acc[0][ct] = __builtin_amdgcn_mfma_f32_16x16x32_bf16(a0, bb, acc[0][ct], 0, 0, 0);
        acc[1][ct] = __builtin_amdgcn_mfma_f32_16x16x32_bf16(a1, bb, acc[1][ct], 0, 0, 0);
      }
    }
    __syncthreads();
  }

  float bias_c[4];
#pragma unroll
  for (int ct = 0; ct < 4; ++ct) {
    int col = col0 + ct * 16 + l16;
    float b = g.bias ? g.bias[col] : 0.f;
    if (g.bias2) b += g.bias2[col];
    bias_c[ct] = b;
  }
#pragma unroll
  for (int rt = 0; rt < 2; ++rt)
#pragma unroll
    for (int r = 0; r < 4; ++r) {
      size_t row = row0 + w * 32 + rt * 16 + quad * 4 + r;
#pragma unroll
      for (int ct = 0; ct < 4; ++ct) {
        int col = col0 + ct * 16 + l16;
        float v = acc[rt][ct][r] + bias_c[ct];
        if (g.add) v += g.add[row * g.Ncols + col];
        if (g.gelu) v = 0.5f * v * (1.f + erff(v * 0.70710678118654752f));
        if (g.obf) ((unsigned short*)g.C)[row * g.Ncols + col] = f2b(v);
        else       ((float*)g.C)[row * g.Ncols + col] = v;
      }
    }
}

// ======================= fused FF: H = hr + W2@gelu(W1@hr+b1)+b2 =======================
// block 256 (4 waves), 64 rows/block; intermediate (128..) stays in LDS bf16.
struct FFPack {
  const float *HN, *W1, *b1, *W2, *b2;
  float* H;
};

__global__ __launch_bounds__(256) void ff_fused(FFPack p) {
  const int t = blockIdx.y;
  const int row0 = blockIdx.x * 64;
  const int tid = threadIdx.x;
  const int w = tid >> 6, lane = tid & 63;
  const int l16 = lane & 15, quad = lane >> 4;

  const float* A  = p.HN + ((size_t)t * NN) * 64;
  const float* W1 = p.W1 + (size_t)t * 64 * 256;
  const float* b1 = p.b1 + t * 256;
  const float* W2 = p.W2 + (size_t)t * 256 * 64;
  const float* b2 = p.b2 + t * 64;

  __shared__ __bf16 As[64 * LDA];
  __shared__ __bf16 A2[64 * LDA];
  __shared__ __bf16 B1s[64 * LDA];
  __shared__ __bf16 B2s[64 * LDA];

  // stage hr rows (f32 -> bf16)
#pragma unroll
  for (int it = 0; it < 4; ++it) {
    int fi = it * 256 + tid;           // 0..1023
    int grow = fi >> 4;
    int kq = (fi & 15) << 2;
    float4 a = *(const float4*)(A + (size_t)(row0 + grow) * 64 + kq);
    v4bf c = { (__bf16)a.x, (__bf16)a.y, (__bf16)a.z, (__bf16)a.w };
    *(v4bf*)&As[grow * LDA + kq] = c;
  }

  v4f acc2[4];
#pragma unroll
  for (int ct = 0; ct < 4; ++ct)
#pragma unroll
    for (int r = 0; r < 4; ++r) acc2[ct][r] = 0.f;

  for (int c1 = 0; c1 < 4; ++c1) {
    // stage W1 tile (k=0..63, cols c1*64..) and W2 K-tile (rows c1*64..), both transposed
#pragma unroll
    for (int it = 0; it < 4; ++it) {
      int fi = it * 256 + tid;
      int kk = fi >> 4;
      int nq = (fi & 15) << 2;
      float4 b = *(const float4*)(W1 + (size_t)kk * 256 + c1 * 64 + nq);
      B1s[(nq + 0) * LDA + kk] = (__bf16)b.x;
      B1s[(nq + 1) * LDA + kk] = (__bf16)b.y;
      B1s[(nq + 2) * LDA + kk] = (__bf16)b.z;
      B1s[(nq + 3) * LDA + kk] = (__bf16)b.w;
      float4 b2v = *(const float4*)(W2 + (size_t)(c1 * 64 + kk) * 64 + nq);
      B2s[(nq + 0) * LDA + kk] = (__bf16)b2v.x;
      B2s[(nq + 1) * LDA + kk] = (__bf16)b2v.y;
      B2s[(nq + 2) * LDA + kk] = (__bf16)b2v.z;
      B2s[(nq + 3) * LDA + kk] = (__bf16)b2v.w;
    }
    __syncthreads();

    // GEMM1: 64x64 rows x (this 64-slice of intermediate)
    v4f acc1[4];
#pragma unroll
    for (int ct = 0; ct < 4; ++ct)
#pragma unroll
      for (int r = 0; r < 4; ++r) acc1[ct][r] = 0.f;
#pragma unroll
    for (int ks = 0; ks < 2; ++ks) {
      v8bf a = *(v8bf*)&As[(w * 16 + l16) * LDA + ks * 32 + quad * 8];
#pragma unroll
      for (int ct = 0; ct < 4; ++ct) {
        v8bf bb = *(v8bf*)&B1s[(ct * 16 + l16) * LDA + ks * 32 + quad * 8];
        acc1[ct] = __builtin_amdgcn_mfma_f32_16x16x32_bf16(a, bb, acc1[ct], 0, 0, 0);
      }
    }
    // bias + gelu -> A2 (own wave rows only)
#pragma unroll
    for (int ct = 0; ct < 4; ++ct) {
      float bb = b1[c1 * 64 + ct * 16 + l16];
#pragma unroll
      for (int r = 0; r < 4; ++r) {
        float v = acc1[ct][r] + bb;
        v = 0.5f * v * (1.f + erff(v * 0.70710678118654752f));
        A2[(w * 16 + quad * 4 + r) * LDA + ct * 16 + l16] = (__bf16)v;
      }
    }
    // GEMM2 accumulate: A2(own rows) x B2s
#pragma unroll
    for (int ks = 0; ks < 2; ++ks) {
      v8bf a = *(v8bf*)&A2[(w * 16 + l16) * LDA + ks * 32 + quad * 8];
#pragma unroll
      for (int ct = 0; ct < 4; ++ct) {
        v8bf bb = *(v8bf*)&B2s[(ct * 16 + l16) * LDA + ks * 32 + quad * 8];
        acc2[ct] = __builtin_amdgcn_mfma_f32_16x16x32_bf16(a, bb, acc2[ct], 0, 0, 0);
      }
    }
    __syncthreads();
  }

  // epilogue: H = hr (re-read f32) + acc2 + b2
#pragma unroll
  for (int ct = 0; ct < 4; ++ct) {
    int col = ct * 16 + l16;
    float bb = b2[col];
#pragma unroll
    for (int r = 0; r < 4; ++r) {
      size_t row = (size_t)t * NN + row0 + w * 16 + quad * 4 + r;
      float v = acc2[ct][r] + bb + p.HN[row * 64 + col];
      p.H[row * 64 + col] = v;
    }
  }
}

// ======================= edge aggregation + beta-gate + LayerNorm =======================
// one wave / dst node; lane = head*16 + c4; two online-softmax streams.
struct AggPack {
  const unsigned short *Q, *K, *V;
  const float *R, *Wb, *Hin, *lng, *lnb;
  float* outHR;
  const int *rowptr, *colsrc;
};

__global__ __launch_bounds__(256) void agg_kernel(AggPack p) {
  int wid = threadIdx.x >> 6;
  int lane = threadIdx.x & 63;
  int node = blockIdx.x * 4 + wid;
  int c4 = lane & 15;
  int cb = ((lane >> 4) << 6) + (c4 << 2);   // head*64 + c4*4

  int start = p.rowptr[node], end = p.rowptr[node + 1];
  int len = end - start;
  int n2 = len >> 1;
  int j0 = start, j1 = start + n2;
  int e0 = start + n2, e1 = end;

  ushort4 qu = *(const ushort4*)(p.Q + ((size_t)node << 8) + cb);
  float qx = b2f(qu.x), qy = b2f(qu.y), qz = b2f(qu.z), qw = b2f(qu.w);

  float m0 = -1e30f, d0 = 0.f, a0x = 0.f, a0y = 0.f, a0z = 0.f, a0w = 0.f;
  float m1 = -1e30f, d1 = 0.f, a1x = 0.f, a1y = 0.f, a1z = 0.f, a1w = 0.f;

  ushort4 kp0, vp0, kp1, vp1;
  if (j0 < e0) {
    int s = p.colsrc[j0];
    kp0 = *(const ushort4*)(p.K + ((size_t)s << 8) + cb);
    vp0 = *(const ushort4*)(p.V + ((size_t)s << 8) + cb);
  }
  if (j1 < e1) {
    int s = p.colsrc[j1];
    kp1 = *(const ushort4*)(p.K + ((size_t)s << 8) + cb);
    vp1 = *(const ushort4*)(p.V + ((size_t)s << 8) + cb);
  }

  for (int it = 0; it < n2; ++it) {
    ushort4 k0 = kp0, v0 = vp0, k1 = kp1, v1 = vp1;
    if (j0 + 1 < e0) {
      int s = p.colsrc[j0 + 1];
      kp0 = *(const ushort4*)(p.K + ((size_t)s << 8) + cb);
      vp0 = *(const ushort4*)(p.V + ((size_t)s << 8) + cb);
    }
    if (j1 + 1 < e1) {
      int s = p.colsrc[j1 + 1];
      kp1 = *(const ushort4*)(p.K + ((size_t)s << 8) + cb);
      vp1 = *(const ushort4*)(p.V + ((size_t)s << 8) + cb);
    }
    float pd0 = qx * b2f(k0.x) + qy * b2f(k0.y) + qz * b2f(k0.z) + qw * b2f(k0.w);
    float pd1 = qx * b2f(k1.x) + qy * b2f(k1.y) + qz * b2f(k1.z) + qw * b2f(k1.w);
    pd0 += __shfl_xor(pd0, 1); pd1 += __shfl_xor(pd1, 1);
    pd0 += __shfl_xor(pd0, 2); pd1 += __shfl_xor(pd1, 2);
    pd0 += __shfl_xor(pd0, 4); pd1 += __shfl_xor(pd1, 4);
    pd0 += __shfl_xor(pd0, 8); pd1 += __shfl_xor(pd1, 8);
    float lg0 = pd0 * 0.125f, lg1 = pd1 * 0.125f;
    {
      float nm = fmaxf(m0, lg0);
      float sc = __expf(m0 - nm), wg = __expf(lg0 - nm);
      m0 = nm;
      d0 = d0 * sc + wg;
      a0x = a0x * sc + wg * b2f(v0.x);
      a0y = a0y * sc + wg * b2f(v0.y);
      a0z = a0z * sc + wg * b2f(v0.z);
      a0w = a0w * sc + wg * b2f(v0.w);
    }
    {
      float nm = fmaxf(m1, lg1);
      float sc = __expf(m1 - nm), wg = __expf(lg1 - nm);
      m1 = nm;
      d1 = d1 * sc + wg;
      a1x = a1x * sc + wg * b2f(v1.x);
      a1y = a1y * sc + wg * b2f(v1.y);
      a1z = a1z * sc + wg * b2f(v1.z);
      a1w = a1w * sc + wg * b2f(v1.w);
    }
    ++j0; ++j1;
  }
  if (len & 1) {
    float pd1 = qx * b2f(kp1.x) + qy * b2f(kp1.y) + qz * b2f(kp1.z) + qw * b2f(kp1.w);
    pd1 += __shfl_xor(pd1, 1);
    pd1 += __shfl_xor(pd1, 2);
    pd1 += __shfl_xor(pd1, 4);
    pd1 += __shfl_xor(pd1, 8);
    float lg1 = pd1 * 0.125f;
    float nm = fmaxf(m1, lg1);
    float sc = __expf(m1 - nm), wg = __expf(lg1 - nm);
    m1 = nm;
    d1 = d1 * sc + wg;
    a1x = a1x * sc + wg * b2f(vp1.x);
    a1y = a1y * sc + wg * b2f(vp1.y);
    a1z = a1z * sc + wg * b2f(vp1.z);
    a1w = a1w * sc + wg * b2f(vp1.w);
  }
  // merge streams
  float mm = fmaxf(m0, m1);
  float s0 = __expf(m0 - mm), s1 = __expf(m1 - mm);
  float dnm = d0 * s0 + d1 * s1;
  float ax = a0x * s0 + a1x * s1;
  float ay = a0y * s0 + a1y * s1;
  float az = a0z * s0 + a1z * s1;
  float aw = a0w * s0 + a1w * s1;

  float inv = (len > 0) ? (0.25f / dnm) : 0.f;
  float ox = ax * inv, oy = ay * inv, oz = az * inv, ow = aw * inv;
  ox += __shfl_xor(ox, 16); ox += __shfl_xor(ox, 32);
  oy += __shfl_xor(oy, 16); oy += __shfl_xor(oy, 32);
  oz += __shfl_xor(oz, 16); oz += __shfl_xor(oz, 32);
  ow += __shfl_xor(ow, 16); ow += __shfl_xor(ow, 32);

  int cc = c4 << 2;
  float4 r = *(const float4*)(p.R + (size_t)node * 64 + cc);
  const float* wb = p.Wb;
  float part = ox * wb[cc] + oy * wb[cc + 1] + oz * wb[cc + 2] + ow * wb[cc + 3]
             + r.x * wb[64 + cc] + r.y * wb[64 + cc + 1]
             + r.z * wb[64 + cc + 2] + r.w * wb[64 + cc + 3]
             + (ox - r.x) * wb[128 + cc] + (oy - r.y) * wb[128 + cc + 1]
             + (oz - r.z) * wb[128 + cc + 2] + (ow - r.w) * wb[128 + cc + 3];
  part += __shfl_xor(part, 1);
  part += __shfl_xor(part, 2);
  part += __shfl_xor(part, 4);
  part += __shfl_xor(part, 8);
  float beta = 1.f / (1.f + __expf(-part));

  // hn = beta*r + (1-beta)*out ; then hr = LN(h + hn)
  float4 hv = *(const float4*)(p.Hin + (size_t)node * 64 + cc);
  float yx = hv.x + beta * r.x + (1.f - beta) * ox;
  float yy = hv.y + beta * r.y + (1.f - beta) * oy;
  float yz = hv.z + beta * r.z + (1.f - beta) * oz;
  float yw = hv.w + beta * r.w + (1.f - beta) * ow;
  float s = yx + yy + yz + yw;
  s += __shfl_xor(s, 1); s += __shfl_xor(s, 2);
  s += __shfl_xor(s, 4); s += __shfl_xor(s, 8);
  float mu = s * (1.f / 64.f);
  float dx = yx - mu, dy = yy - mu, dz = yz - mu, dw = yw - mu;
  float s2 = dx * dx + dy * dy + dz * dz + dw * dw;
  s2 += __shfl_xor(s2, 1); s2 += __shfl_xor(s2, 2);
  s2 += __shfl_xor(s2, 4); s2 += __shfl_xor(s2, 8);
  float rs = rsqrtf(s2 * (1.f / 64.f) + 1e-5f);
  if (lane < 16) {
    float4 gg = *(const float4*)(p.lng + cc);
    float4 bb = *(const float4*)(p.lnb + cc);
    float4 res;
    res.x = dx * rs * gg.x + bb.x;
    res.y = dy * rs * gg.y + bb.y;
    res.z = dz * rs * gg.z + bb.z;
    res.w = dw * rs * gg.w + bb.w;
    *(float4*)(p.outHR + (size_t)node * 64 + cc) = res;
  }
}

// ======================= host =======================
static void add_desc(GemmPack& p, int& tiles, const float* A, const float* B,
                     const float* bias, const float* bias2, const float* add,
                     void* C, int K, int Nc, int gelu, int obf) {
  GemmDesc& g = p.d[p.nd++];
  g.A = A; g.B = B; g.bias = bias; g.bias2 = bias2; g.add = add; g.C = C;
  g.K = K; g.Ncols = Nc; g.tile0 = tiles; g.ntiles = Nc / 64; g.gelu = gelu;
  g.obf = obf;
  tiles += g.ntiles;
}

extern "C" void kernel_launch(void* const* d_in, const int* in_sizes, int n_in,
                              void* d_out, int out_size, void* d_ws, size_t ws_size,
                              hipStream_t stream) {
  const float* x        = (const float*)d_in[0];
  const int*   ei       = (const int*)d_in[1];
  const float* W_in     = (const float*)d_in[2];
  const float* b_in     = (const float*)d_in[3];
  const float* type_emb = (const float*)d_in[4];
  const float* pos      = (const float*)d_in[5];
  const float* Wq       = (const float*)d_in[6];
  const float* bq       = (const float*)d_in[7];
  const float* Wk       = (const float*)d_in[8];
  const float* bk       = (const float*)d_in[9];
  const float* Wv       = (const float*)d_in[10];
  const float* bv       = (const float*)d_in[11];
  const float* Wskip    = (const float*)d_in[12];
  const float* bskip    = (const float*)d_in[13];
  const float* Wbeta    = (const float*)d_in[14];
  const float* ln_g     = (const float*)d_in[15];
  const float* ln_b     = (const float*)d_in[16];
  const float* ff_W1    = (const float*)d_in[17];
  const float* ff_b1    = (const float*)d_in[18];
  const float* ff_W2    = (const float*)d_in[19];
  const float* ff_b2    = (const float*)d_in[20];
  const float* W_out    = (const float*)d_in[21];
  const float* b_out    = (const float*)d_in[22];
  float* out = (float*)d_out;

  int*   wsi = (int*)d_ws;
  float* wsf = (float*)d_ws;
  int* cnt    = wsi + OFF_CNT;
  int* fill   = wsi + OFF_FILL;
  int* rowptr = wsi + OFF_ROWPTR;
  int* colsrc = wsi + OFF_COLSRC;
  float* H  = wsf + OFF_H;
  float* HN = wsf + OFF_HN;
  unsigned short* Qb = (unsigned short*)(wsf + OFF_Q);
  unsigned short* Kb = (unsigned short*)(wsf + OFF_K);
  unsigned short* Vb = (unsigned short*)(wsf + OFF_V);
  float* Rb = wsf + OFF_R;

  // ---- CSR build ----
  hipMemsetAsync(cnt, 0, 2 * NN * sizeof(int), stream);
  count_kernel<<<dim3(2 * EE / 256), dim3(256), 0, stream>>>(ei, cnt);
  scan_kernel<<<dim3(2), dim3(1024), 0, stream>>>(cnt, rowptr, fill);
  scatter_kernel<<<dim3(2 * EE / 256), dim3(256), 0, stream>>>(ei, fill, colsrc);

  // ---- input projection ----
  {
    GemmPack p{}; int tiles = 0;
    for (int t = 0; t < 2; ++t)
      add_desc(p, tiles, x + (size_t)t * NN * 64, W_in + t * 64 * 64,
               b_in + t * 64, type_emb + t * 64, pos + (size_t)t * NN * 64,
               H + (size_t)t * NN * 64, 64, 64, 0, 0);
    gemm_mfma<<<dim3(128, tiles), dim3(256), 0, stream>>>(p);
  }

  for (int l = 0; l < 2; ++l) {
    for (int et = 0; et < 2; ++et) {
      int s = et, d = 1 - et;
      int we = l * 2 + et;
      const float* hs = H + (size_t)s * NN * 64;
      const float* hd = H + (size_t)d * NN * 64;
      GemmPack p{}; int tiles = 0;
      add_desc(p, tiles, hd, Wq + (size_t)we * 64 * 256, bq + we * 256,
               nullptr, nullptr, Qb, 64, 256, 0, 1);
      add_desc(p, tiles, hs, Wk + (size_t)we * 64 * 256, bk + we * 256,
               nullptr, nullptr, Kb, 64, 256, 0, 1);
      add_desc(p, tiles, hs, Wv + (size_t)we * 64 * 256, bv + we * 256,
               nullptr, nullptr, Vb, 64, 256, 0, 1);
      add_desc(p, tiles, hd, Wskip + (size_t)we * 64 * 64, bskip + we * 64,
               nullptr, nullptr, Rb, 64, 64, 0, 0);
      gemm_mfma<<<dim3(128, tiles), dim3(256), 0, stream>>>(p);

      AggPack ap;
      ap.Q = Qb; ap.K = Kb; ap.V = Vb; ap.R = Rb;
      ap.Wb = Wbeta + we * 192;
      ap.Hin = H + (size_t)d * NN * 64;
      ap.lng = ln_g + (l * 2 + d) * 64;
      ap.lnb = ln_b + (l * 2 + d) * 64;
      ap.outHR = HN + (size_t)d * NN * 64;
      ap.rowptr = rowptr + et * (NN + 1);
      ap.colsrc = colsrc + et * EE;
      agg_kernel<<<dim3(NN / 4), dim3(256), 0, stream>>>(ap);
    }

    FFPack fp;
    fp.HN = HN;
    fp.W1 = ff_W1 + (size_t)l * 2 * 64 * 256;
    fp.b1 = ff_b1 + l * 2 * 256;
    fp.W2 = ff_W2 + (size_t)l * 2 * 256 * 64;
    fp.b2 = ff_b2 + l * 2 * 64;
    fp.H  = H;
    ff_fused<<<dim3(NN / 64, 2), dim3(256), 0, stream>>>(fp);
  }

  // ---- output projection ----
  {
    GemmPack p{}; int tiles = 0;
    for (int t = 0; t < 2; ++t)
      add_desc(p, tiles, H + (size_t)t * NN * 64, W_out + t * 64 * 64,
               b_out + t * 64, nullptr, nullptr,
               out + (size_t)t * NN * 64, 64, 64, 0, 0);
    gemm_mfma<<<dim3(128, tiles), dim3(256), 0, stream>>>(p);
  }
}

// Round 4
// 418.168 us; speedup vs baseline: 1.8094x; 1.1335x over previous
//
#include <hip/hip_runtime.h>
#include <math.h>

#define NN 16384
#define EE 262144

typedef __bf16 v8bf __attribute__((ext_vector_type(8)));
typedef __bf16 v4bf __attribute__((ext_vector_type(4)));
typedef float  v4f  __attribute__((ext_vector_type(4)));

// ---- workspace layout (units of 4-byte elements) ----
#define OFF_CNT     0                         // 2*NN ints
#define OFF_FILL    (2*NN)                    // 2*NN ints
#define OFF_ROWPTR  (4*NN)                    // 2*(NN+1) ints
#define OFF_COLSRC  98816                     // 2*EE ints (byte offsets)
#define OFF_H       623104                    // 2*NN*64 f32
#define OFF_HN      (OFF_H  + 2*NN*64)        // 2*NN*64 f32
#define OFF_Q       (OFF_HN + 2*NN*64)        // 2*NN*256 bf16 = 2*NN*128 f32 slots
#define OFF_KV      (OFF_Q  + 2*NN*128)       // 2*NN*512 bf16 = 2*NN*256 f32 slots
#define OFF_R       (OFF_KV + 2*NN*256)       // 2*NN*64 f32

__device__ __forceinline__ float blo(unsigned u) { return __uint_as_float(u << 16); }
__device__ __forceinline__ float bhi(unsigned u) { return __uint_as_float(u & 0xffff0000u); }
__device__ __forceinline__ unsigned short f2b(float f) {
  __bf16 h = (__bf16)f;
  return *(unsigned short*)&h;
}

// ======================= CSR build =======================
__global__ void count_kernel(const int* __restrict__ ei, int* __restrict__ cnt) {
  int idx = blockIdx.x * 256 + threadIdx.x;
  if (idx >= 2 * EE) return;
  int et = idx >> 18;
  int j  = idx & (EE - 1);
  int dst = ei[et * 2 * EE + EE + j];
  atomicAdd(&cnt[et * NN + dst], 1);
}

__global__ __launch_bounds__(1024) void scan_kernel(const int* __restrict__ cnt,
                                                    int* __restrict__ rowptr,
                                                    int* __restrict__ fill) {
  int et = blockIdx.x;
  const int* c = cnt + et * NN;
  __shared__ int sums[1024];
  int tid = threadIdx.x;
  int base = tid * 16;
  int loc[16];
  int s = 0;
#pragma unroll
  for (int i = 0; i < 16; ++i) { loc[i] = s; s += c[base + i]; }
  sums[tid] = s;
  __syncthreads();
  for (int off = 1; off < 1024; off <<= 1) {
    int v = 0;
    if (tid >= off) v = sums[tid - off];
    __syncthreads();
    if (tid >= off) sums[tid] += v;
    __syncthreads();
  }
  int ebase = (tid == 0) ? 0 : sums[tid - 1];
  int* rp = rowptr + et * (NN + 1);
  int* fl = fill + et * NN;
#pragma unroll
  for (int i = 0; i < 16; ++i) {
    rp[base + i] = ebase + loc[i];
    fl[base + i] = ebase + loc[i];
  }
  if (tid == 1023) rp[NN] = sums[1023];
}

// colsrc holds BYTE offset of the src node's KV row: (et*NN + src) << 10
__global__ void scatter_kernel(const int* __restrict__ ei, int* __restrict__ fill,
                               int* __restrict__ colsrc) {
  int idx = blockIdx.x * 256 + threadIdx.x;
  if (idx >= 2 * EE) return;
  int et = idx >> 18;
  int j  = idx & (EE - 1);
  int src = ei[et * 2 * EE + j];
  int dst = ei[et * 2 * EE + EE + j];
  int pos = atomicAdd(&fill[et * NN + dst], 1);
  colsrc[et * EE + pos] = (et * NN + src) << 10;
}

// ======================= bf16 MFMA tiled GEMM =======================
struct GemmDesc {
  const float *A, *B, *bias, *bias2, *add;
  void* C;
  int K, Ncols, Cld, tile0, ntiles, gelu, obf;
};
struct GemmPack { GemmDesc d[8]; int nd; };

#define LDA 72   // padded bf16 row stride

__global__ __launch_bounds__(256) void gemm_mfma(GemmPack p) {
  int y = blockIdx.y;
  int di = 0;
  for (int i = 0; i < p.nd; ++i)
    if (y >= p.d[i].tile0 && y < p.d[i].tile0 + p.d[i].ntiles) di = i;
  GemmDesc g = p.d[di];
  const int col0 = (y - g.tile0) * 64;
  const int row0 = blockIdx.x * 128;
  const int tid = threadIdx.x;
  const int w = tid >> 6, lane = tid & 63;
  const int l16 = lane & 15, quad = lane >> 4;

  __shared__ __bf16 As[128 * LDA];
  __shared__ __bf16 Bs[64 * LDA];

  v4f acc[2][4];
#pragma unroll
  for (int rt = 0; rt < 2; ++rt)
#pragma unroll
    for (int ct = 0; ct < 4; ++ct)
#pragma unroll
      for (int r = 0; r < 4; ++r) acc[rt][ct][r] = 0.f;

  for (int kt = 0; kt < g.K; kt += 64) {
#pragma unroll
    for (int it = 0; it < 8; ++it) {
      int fi = it * 256 + tid;
      int grow = fi >> 4;
      int kq = (fi & 15) << 2;
      float4 a = *(const float4*)(g.A + (size_t)(row0 + grow) * g.K + kt + kq);
      v4bf c = { (__bf16)a.x, (__bf16)a.y, (__bf16)a.z, (__bf16)a.w };
      *(v4bf*)&As[grow * LDA + kq] = c;
    }
#pragma unroll
    for (int it = 0; it < 4; ++it) {
      int fi = it * 256 + tid;
      int kk = fi >> 4;
      int nq = (fi & 15) << 2;
      float4 b = *(const float4*)(g.B + (size_t)(kt + kk) * g.Ncols + col0 + nq);
      Bs[(nq + 0) * LDA + kk] = (__bf16)b.x;
      Bs[(nq + 1) * LDA + kk] = (__bf16)b.y;
      Bs[(nq + 2) * LDA + kk] = (__bf16)b.z;
      Bs[(nq + 3) * LDA + kk] = (__bf16)b.w;
    }
    __syncthreads();
#pragma unroll
    for (int ks = 0; ks < 2; ++ks) {
      v8bf a0 = *(v8bf*)&As[(w * 32 + l16) * LDA + ks * 32 + quad * 8];
      v8bf a1 = *(v8bf*)&As[(w * 32 + 16 + l16) * LDA + ks * 32 + quad * 8];
#pragma unroll
      for (int ct = 0; ct < 4; ++ct) {
        v8bf bb = *(v8bf*)&Bs[(ct * 16 + l16) * LDA + ks * 32 + quad * 8];
        acc[0][ct] = __builtin_amdgcn_mfma_f32_16x16x32_bf16(a0, bb, acc[0][ct], 0, 0, 0);
        acc[1][ct] = __builtin_amdgcn_mfma_f32_16x16x32_bf16(a1, bb, acc[1][ct], 0, 0, 0);
      }
    }
    __syncthreads();
  }

  float bias_c[4];
#pragma unroll
  for (int ct = 0; ct < 4; ++ct) {
    int col = col0 + ct * 16 + l16;
    float b = g.bias ? g.bias[col] : 0.f;
    if (g.bias2) b += g.bias2[col];
    bias_c[ct] = b;
  }
#pragma unroll
  for (int rt = 0; rt < 2; ++rt)
#pragma unroll
    for (int r = 0; r < 4; ++r) {
      size_t row = row0 + w * 32 + rt * 16 + quad * 4 + r;
#pragma unroll
      for (int ct = 0; ct < 4; ++ct) {
        int col = col0 + ct * 16 + l16;
        float v = acc[rt][ct][r] + bias_c[ct];
        if (g.add) v += g.add[row * g.Ncols + col];
        if (g.gelu) v = 0.5f * v * (1.f + erff(v * 0.70710678118654752f));
        if (g.obf) ((unsigned short*)g.C)[row * g.Cld + col] = f2b(v);
        else       ((float*)g.C)[row * g.Cld + col] = v;
      }
    }
}

// ======================= fused FF =======================
struct FFPack {
  const float *HN, *W1, *b1, *W2, *b2;
  float* H;
};

__global__ __launch_bounds__(256) void ff_fused(FFPack p) {
  const int t = blockIdx.y;
  const int row0 = blockIdx.x * 64;
  const int tid = threadIdx.x;
  const int w = tid >> 6, lane = tid & 63;
  const int l16 = lane & 15, quad = lane >> 4;

  const float* A  = p.HN + ((size_t)t * NN) * 64;
  const float* W1 = p.W1 + (size_t)t * 64 * 256;
  const float* b1 = p.b1 + t * 256;
  const float* W2 = p.W2 + (size_t)t * 256 * 64;
  const float* b2 = p.b2 + t * 64;

  __shared__ __bf16 As[64 * LDA];
  __shared__ __bf16 A2[64 * LDA];
  __shared__ __bf16 B1s[64 * LDA];
  __shared__ __bf16 B2s[64 * LDA];

#pragma unroll
  for (int it = 0; it < 4; ++it) {
    int fi = it * 256 + tid;
    int grow = fi >> 4;
    int kq = (fi & 15) << 2;
    float4 a = *(const float4*)(A + (size_t)(row0 + grow) * 64 + kq);
    v4bf c = { (__bf16)a.x, (__bf16)a.y, (__bf16)a.z, (__bf16)a.w };
    *(v4bf*)&As[grow * LDA + kq] = c;
  }

  v4f acc2[4];
#pragma unroll
  for (int ct = 0; ct < 4; ++ct)
#pragma unroll
    for (int r = 0; r < 4; ++r) acc2[ct][r] = 0.f;

  for (int c1 = 0; c1 < 4; ++c1) {
#pragma unroll
    for (int it = 0; it < 4; ++it) {
      int fi = it * 256 + tid;
      int kk = fi >> 4;
      int nq = (fi & 15) << 2;
      float4 b = *(const float4*)(W1 + (size_t)kk * 256 + c1 * 64 + nq);
      B1s[(nq + 0) * LDA + kk] = (__bf16)b.x;
      B1s[(nq + 1) * LDA + kk] = (__bf16)b.y;
      B1s[(nq + 2) * LDA + kk] = (__bf16)b.z;
      B1s[(nq + 3) * LDA + kk] = (__bf16)b.w;
      float4 b2v = *(const float4*)(W2 + (size_t)(c1 * 64 + kk) * 64 + nq);
      B2s[(nq + 0) * LDA + kk] = (__bf16)b2v.x;
      B2s[(nq + 1) * LDA + kk] = (__bf16)b2v.y;
      B2s[(nq + 2) * LDA + kk] = (__bf16)b2v.z;
      B2s[(nq + 3) * LDA + kk] = (__bf16)b2v.w;
    }
    __syncthreads();

    v4f acc1[4];
#pragma unroll
    for (int ct = 0; ct < 4; ++ct)
#pragma unroll
      for (int r = 0; r < 4; ++r) acc1[ct][r] = 0.f;
#pragma unroll
    for (int ks = 0; ks < 2; ++ks) {
      v8bf a = *(v8bf*)&As[(w * 16 + l16) * LDA + ks * 32 + quad * 8];
#pragma unroll
      for (int ct = 0; ct < 4; ++ct) {
        v8bf bb = *(v8bf*)&B1s[(ct * 16 + l16) * LDA + ks * 32 + quad * 8];
        acc1[ct] = __builtin_amdgcn_mfma_f32_16x16x32_bf16(a, bb, acc1[ct], 0, 0, 0);
      }
    }
#pragma unroll
    for (int ct = 0; ct < 4; ++ct) {
      float bb = b1[c1 * 64 + ct * 16 + l16];
#pragma unroll
      for (int r = 0; r < 4; ++r) {
        float v = acc1[ct][r] + bb;
        v = 0.5f * v * (1.f + erff(v * 0.70710678118654752f));
        A2[(w * 16 + quad * 4 + r) * LDA + ct * 16 + l16] = (__bf16)v;
      }
    }
#pragma unroll
    for (int ks = 0; ks < 2; ++ks) {
      v8bf a = *(v8bf*)&A2[(w * 16 + l16) * LDA + ks * 32 + quad * 8];
#pragma unroll
      for (int ct = 0; ct < 4; ++ct) {
        v8bf bb = *(v8bf*)&B2s[(ct * 16 + l16) * LDA + ks * 32 + quad * 8];
        acc2[ct] = __builtin_amdgcn_mfma_f32_16x16x32_bf16(a, bb, acc2[ct], 0, 0, 0);
      }
    }
    __syncthreads();
  }

#pragma unroll
  for (int ct = 0; ct < 4; ++ct) {
    int col = ct * 16 + l16;
    float bb = b2[col];
#pragma unroll
    for (int r = 0; r < 4; ++r) {
      size_t row = (size_t)t * NN + row0 + w * 16 + quad * 4 + r;
      float v = acc2[ct][r] + bb + p.HN[row * 64 + col];
      p.H[row * 64 + col] = v;
    }
  }
}

// ======================= edge aggregation + beta + LN =======================
// grid.y = edge type; one wave / dst node; lane = head*16 + c4.
// No-max softmax (logits provably tiny): d += exp(l), acc += exp(l)*v.
// 4 independent streams, uniform (scalar) loop bounds, predicated weights.
struct AggPack {
  const unsigned short *Q;   // [2*NN][256] bf16 (dst-type indexed)
  const unsigned short *KV;  // [2*NN][512] bf16 (src-type indexed, K|V)
  const float *R;            // [2*NN][64]
  const float *Wb;           // + et*192 in kernel
  const float *Hin;          // H base (both types)
  const float *lng, *lnb;    // + d*64 in kernel
  float* outHR;              // HN base
  const int *rowptr;         // [2][NN+1]
  const int *colsrc;         // [2][EE] byte offsets
};

__global__ __launch_bounds__(256) void agg_kernel(AggPack p) {
  const int et = blockIdx.y, d = 1 - et;
  int wid = __builtin_amdgcn_readfirstlane(threadIdx.x >> 6);
  int lane = threadIdx.x & 63;
  int node = blockIdx.x * 4 + wid;
  int c4 = lane & 15;
  int cb = ((lane >> 4) << 6) + (c4 << 2);   // head*64 + c4*4

  const int* rp = p.rowptr + et * (NN + 1);
  const int* cs = p.colsrc + et * EE;
  int start = rp[node], end = rp[node + 1];
  int len = end - start;

  int gnode = d * NN + node;
  uint2 qw = *(const uint2*)(p.Q + ((size_t)gnode << 8) + cb);
  float q0 = blo(qw.x) * 0.125f, q1 = bhi(qw.x) * 0.125f;
  float q2 = blo(qw.y) * 0.125f, q3 = bhi(qw.y) * 0.125f;

  int b[5];
#pragma unroll
  for (int i = 0; i <= 4; ++i) b[i] = start + ((len * i) >> 2);
  float dsum[4] = {0.f, 0.f, 0.f, 0.f};
  float acc[4][4];
#pragma unroll
  for (int s4 = 0; s4 < 4; ++s4)
#pragma unroll
    for (int c = 0; c < 4; ++c) acc[s4][c] = 0.f;

  int maxn = (len + 3) >> 2;
  for (int it = 0; it < maxn; ++it) {
#pragma unroll
    for (int s4 = 0; s4 < 4; ++s4) {
      int j = b[s4] + it;
      bool act = j < b[s4 + 1];
      int jc = act ? j : (end - 1);
      int off = cs[jc];                      // scalar load: KV row byte offset
      const unsigned short* kp = (const unsigned short*)((const char*)p.KV + off) + cb;
      uint2 kw = *(const uint2*)kp;
      uint2 vw = *(const uint2*)(kp + 256);  // V half, +512 B
      float pd = q0 * blo(kw.x) + q1 * bhi(kw.x) + q2 * blo(kw.y) + q3 * bhi(kw.y);
      pd += __shfl_xor(pd, 1);
      pd += __shfl_xor(pd, 2);
      pd += __shfl_xor(pd, 4);
      pd += __shfl_xor(pd, 8);
      float wgt = act ? __expf(pd) : 0.f;
      dsum[s4] += wgt;
      acc[s4][0] += wgt * blo(vw.x);
      acc[s4][1] += wgt * bhi(vw.x);
      acc[s4][2] += wgt * blo(vw.y);
      acc[s4][3] += wgt * bhi(vw.y);
    }
  }
  // exact stream merge (no rescale needed)
  float dn = (dsum[0] + dsum[1]) + (dsum[2] + dsum[3]);
  float ax = (acc[0][0] + acc[1][0]) + (acc[2][0] + acc[3][0]);
  float ay = (acc[0][1] + acc[1][1]) + (acc[2][1] + acc[3][1]);
  float az = (acc[0][2] + acc[1][2]) + (acc[2][2] + acc[3][2]);
  float aw = (acc[0][3] + acc[1][3]) + (acc[2][3] + acc[3][3]);

  float inv = (len > 0) ? (0.25f / dn) : 0.f;
  float ox = ax * inv, oy = ay * inv, oz = az * inv, ow = aw * inv;
  ox += __shfl_xor(ox, 16); ox += __shfl_xor(ox, 32);
  oy += __shfl_xor(oy, 16); oy += __shfl_xor(oy, 32);
  oz += __shfl_xor(oz, 16); oz += __shfl_xor(oz, 32);
  ow += __shfl_xor(ow, 16); ow += __shfl_xor(ow, 32);

  int cc = c4 << 2;
  float4 r = *(const float4*)(p.R + (size_t)gnode * 64 + cc);
  const float* wb = p.Wb + et * 192;
  float part = ox * wb[cc] + oy * wb[cc + 1] + oz * wb[cc + 2] + ow * wb[cc + 3]
             + r.x * wb[64 + cc] + r.y * wb[64 + cc + 1]
             + r.z * wb[64 + cc + 2] + r.w * wb[64 + cc + 3]
             + (ox - r.x) * wb[128 + cc] + (oy - r.y) * wb[128 + cc + 1]
             + (oz - r.z) * wb[128 + cc + 2] + (ow - r.w) * wb[128 + cc + 3];
  part += __shfl_xor(part, 1);
  part += __shfl_xor(part, 2);
  part += __shfl_xor(part, 4);
  part += __shfl_xor(part, 8);
  float beta = 1.f / (1.f + __expf(-part));

  float4 hv = *(const float4*)(p.Hin + (size_t)gnode * 64 + cc);
  float yx = hv.x + beta * r.x + (1.f - beta) * ox;
  float yy = hv.y + beta * r.y + (1.f - beta) * oy;
  float yz = hv.z + beta * r.z + (1.f - beta) * oz;
  float yw = hv.w + beta * r.w + (1.f - beta) * ow;
  float s = yx + yy + yz + yw;
  s += __shfl_xor(s, 1); s += __shfl_xor(s, 2);
  s += __shfl_xor(s, 4); s += __shfl_xor(s, 8);
  float mu = s * (1.f / 64.f);
  float dx = yx - mu, dy = yy - mu, dz = yz - mu, dw = yw - mu;
  float s2 = dx * dx + dy * dy + dz * dz + dw * dw;
  s2 += __shfl_xor(s2, 1); s2 += __shfl_xor(s2, 2);
  s2 += __shfl_xor(s2, 4); s2 += __shfl_xor(s2, 8);
  float rs = rsqrtf(s2 * (1.f / 64.f) + 1e-5f);
  if (lane < 16) {
    const float* lng = p.lng + d * 64;
    const float* lnb = p.lnb + d * 64;
    float4 gg = *(const float4*)(lng + cc);
    float4 bb = *(const float4*)(lnb + cc);
    float4 res;
    res.x = dx * rs * gg.x + bb.x;
    res.y = dy * rs * gg.y + bb.y;
    res.z = dz * rs * gg.z + bb.z;
    res.w = dw * rs * gg.w + bb.w;
    *(float4*)(p.outHR + (size_t)gnode * 64 + cc) = res;
  }
}

// ======================= host =======================
static void add_desc(GemmPack& p, int& tiles, const float* A, const float* B,
                     const float* bias, const float* bias2, const float* add,
                     void* C, int K, int Nc, int Cld, int gelu, int obf) {
  GemmDesc& g = p.d[p.nd++];
  g.A = A; g.B = B; g.bias = bias; g.bias2 = bias2; g.add = add; g.C = C;
  g.K = K; g.Ncols = Nc; g.Cld = Cld; g.tile0 = tiles; g.ntiles = Nc / 64;
  g.gelu = gelu; g.obf = obf;
  tiles += g.ntiles;
}

extern "C" void kernel_launch(void* const* d_in, const int* in_sizes, int n_in,
                              void* d_out, int out_size, void* d_ws, size_t ws_size,
                              hipStream_t stream) {
  const float* x        = (const float*)d_in[0];
  const int*   ei       = (const int*)d_in[1];
  const float* W_in     = (const float*)d_in[2];
  const float* b_in     = (const float*)d_in[3];
  const float* type_emb = (const float*)d_in[4];
  const float* pos      = (const float*)d_in[5];
  const float* Wq       = (const float*)d_in[6];
  const float* bq       = (const float*)d_in[7];
  const float* Wk       = (const float*)d_in[8];
  const float* bk       = (const float*)d_in[9];
  const float* Wv       = (const float*)d_in[10];
  const float* bv       = (const float*)d_in[11];
  const float* Wskip    = (const float*)d_in[12];
  const float* bskip    = (const float*)d_in[13];
  const float* Wbeta    = (const float*)d_in[14];
  const float* ln_g     = (const float*)d_in[15];
  const float* ln_b     = (const float*)d_in[16];
  const float* ff_W1    = (const float*)d_in[17];
  const float* ff_b1    = (const float*)d_in[18];
  const float* ff_W2    = (const float*)d_in[19];
  const float* ff_b2    = (const float*)d_in[20];
  const float* W_out    = (const float*)d_in[21];
  const float* b_out    = (const float*)d_in[22];
  float* out = (float*)d_out;

  int*   wsi = (int*)d_ws;
  float* wsf = (float*)d_ws;
  int* cnt    = wsi + OFF_CNT;
  int* fill   = wsi + OFF_FILL;
  int* rowptr = wsi + OFF_ROWPTR;
  int* colsrc = wsi + OFF_COLSRC;
  float* H  = wsf + OFF_H;
  float* HN = wsf + OFF_HN;
  unsigned short* Qb  = (unsigned short*)(wsf + OFF_Q);
  unsigned short* KVb = (unsigned short*)(wsf + OFF_KV);
  float* Rb = wsf + OFF_R;

  // ---- CSR build ----
  hipMemsetAsync(cnt, 0, 2 * NN * sizeof(int), stream);
  count_kernel<<<dim3(2 * EE / 256), dim3(256), 0, stream>>>(ei, cnt);
  scan_kernel<<<dim3(2), dim3(1024), 0, stream>>>(cnt, rowptr, fill);
  scatter_kernel<<<dim3(2 * EE / 256), dim3(256), 0, stream>>>(ei, fill, colsrc);

  // ---- input projection ----
  {
    GemmPack p{}; int tiles = 0;
    for (int t = 0; t < 2; ++t)
      add_desc(p, tiles, x + (size_t)t * NN * 64, W_in + t * 64 * 64,
               b_in + t * 64, type_emb + t * 64, pos + (size_t)t * NN * 64,
               H + (size_t)t * NN * 64, 64, 64, 64, 0, 0);
    gemm_mfma<<<dim3(128, tiles), dim3(256), 0, stream>>>(p);
  }

  for (int l = 0; l < 2; ++l) {
    // one batched GEMM for both edge types: q,k,v,skip x 2
    {
      GemmPack p{}; int tiles = 0;
      for (int et = 0; et < 2; ++et) {
        int s = et, d = 1 - et;
        int we = l * 2 + et;
        const float* hs = H + (size_t)s * NN * 64;
        const float* hd = H + (size_t)d * NN * 64;
        add_desc(p, tiles, hd, Wq + (size_t)we * 64 * 256, bq + we * 256,
                 nullptr, nullptr, Qb + (size_t)d * NN * 256, 64, 256, 256, 0, 1);
        add_desc(p, tiles, hs, Wk + (size_t)we * 64 * 256, bk + we * 256,
                 nullptr, nullptr, KVb + (size_t)s * NN * 512, 64, 256, 512, 0, 1);
        add_desc(p, tiles, hs, Wv + (size_t)we * 64 * 256, bv + we * 256,
                 nullptr, nullptr, KVb + (size_t)s * NN * 512 + 256, 64, 256, 512, 0, 1);
        add_desc(p, tiles, hd, Wskip + (size_t)we * 64 * 64, bskip + we * 64,
                 nullptr, nullptr, Rb + (size_t)d * NN * 64, 64, 64, 64, 0, 0);
      }
      gemm_mfma<<<dim3(128, tiles), dim3(256), 0, stream>>>(p);
    }

    AggPack ap;
    ap.Q = Qb; ap.KV = KVb; ap.R = Rb;
    ap.Wb = Wbeta + l * 2 * 192;
    ap.Hin = H;
    ap.lng = ln_g + l * 128;
    ap.lnb = ln_b + l * 128;
    ap.outHR = HN;
    ap.rowptr = rowptr;
    ap.colsrc = colsrc;
    agg_kernel<<<dim3(NN / 4, 2), dim3(256), 0, stream>>>(ap);

    FFPack fp;
    fp.HN = HN;
    fp.W1 = ff_W1 + (size_t)l * 2 * 64 * 256;
    fp.b1 = ff_b1 + l * 2 * 256;
    fp.W2 = ff_W2 + (size_t)l * 2 * 256 * 64;
    fp.b2 = ff_b2 + l * 2 * 64;
    fp.H  = H;
    ff_fused<<<dim3(NN / 64, 2), dim3(256), 0, stream>>>(fp);
  }

  // ---- output projection ----
  {
    GemmPack p{}; int tiles = 0;
    for (int t = 0; t < 2; ++t)
      add_desc(p, tiles, H + (size_t)t * NN * 64, W_out + t * 64 * 64,
               b_out + t * 64, nullptr, nullptr,
               out + (size_t)t * NN * 64, 64, 64, 64, 0, 0);
    gemm_mfma<<<dim3(128, tiles), dim3(256), 0, stream>>>(p);
  }
}